// Round 1
// baseline (337.122 us; speedup 1.0000x reference)
//
#include <hip/hip_runtime.h>

constexpr int NB  = 16384;  // batch
constexpr int ND  = 3072;   // D
constexpr int NR  = 256;    // R
constexpr int NE  = 8;      // experts
constexpr int NO1 = 16;     // L2+1 outputs of l1
constexpr int NL2D = 30;    // 2*L2
constexpr int NL3 = 32;     // L3

// ---- workspace layout (bytes) ----
constexpr size_t WS_COUNTS  = 0;      // int[8]
constexpr size_t WS_CURSORS = 32;     // int[8]
constexpr size_t WS_SUMP    = 64;     // float[8]
constexpr size_t WS_ZSUM    = 96;     // float
constexpr size_t WS_ENTSUM  = 100;    // float
constexpr size_t WS_TOPSUM  = 104;    // float
constexpr size_t WS_OFFPAD  = 128;    // int[9]
constexpr size_t WS_IDX     = 256;                    // int[NB]
constexpr size_t WS_BUCKET  = WS_IDX + (size_t)NB*4;  // int[NB+256]
constexpr size_t WS_MB      = WS_BUCKET + (size_t)(NB+256)*4; // float[128]
constexpr size_t WS_MW      = WS_MB + 512;            // float[128*3072]

__device__ __forceinline__ float clamp01(float v) { return fminf(fmaxf(v, 0.0f), 1.0f); }

// ---------------- Router: one wave per row batch of 16 ----------------
__global__ __launch_bounds__(256) void router_kernel(
    const float* __restrict__ rin, const float* __restrict__ rw,
    const float* __restrict__ rb, int* __restrict__ idx,
    int* __restrict__ counts, float* __restrict__ sump,
    float* __restrict__ zsum, float* __restrict__ entsum, float* __restrict__ topsum)
{
    const int wave = threadIdx.x >> 6;
    const int lane = threadIdx.x & 63;
    const int e = lane & 7;      // expert this lane computes partial for
    const int g = lane >> 3;     // k-group (8 groups of 32)
    const int b0 = blockIdx.x * 64 + wave * 16;

    float l_sump[NE];
    int   l_cnt[NE];
#pragma unroll
    for (int j = 0; j < NE; ++j) { l_sump[j] = 0.0f; l_cnt[j] = 0; }
    float l_z = 0.0f, l_ent = 0.0f, l_top = 0.0f;

    const float bias = rb[e];

    for (int i = 0; i < 16; ++i) {
        const int b = b0 + i;
        const float* rp = rin + (size_t)b * NR + g * 32;
        const float* wp = rw + (size_t)e * NR + g * 32;
        float part = 0.0f;
#pragma unroll
        for (int c = 0; c < 8; ++c) {
            float4 xv = *(const float4*)(rp + c * 4);
            float4 wv = *(const float4*)(wp + c * 4);
            part = fmaf(xv.x, wv.x, part);
            part = fmaf(xv.y, wv.y, part);
            part = fmaf(xv.z, wv.z, part);
            part = fmaf(xv.w, wv.w, part);
        }
        // reduce over g (lanes with same low-3 bits)
        part += __shfl_xor(part, 8);
        part += __shfl_xor(part, 16);
        part += __shfl_xor(part, 32);
        float logit = part + bias;   // every lane now has full dot for its e

        float lg[NE];
#pragma unroll
        for (int j = 0; j < NE; ++j) lg[j] = __shfl(logit, j);

        // softmax stats (computed redundantly by all lanes)
        float m = lg[0]; int am = 0;
#pragma unroll
        for (int j = 1; j < NE; ++j) { if (lg[j] > m) { m = lg[j]; am = j; } }
        float p[NE]; float ssum = 0.0f;
#pragma unroll
        for (int j = 0; j < NE; ++j) { p[j] = expf(lg[j] - m); ssum += p[j]; }
        const float inv = 1.0f / ssum;
        const float lse = m + logf(ssum);
        l_z += lse * lse;
        float ent = 0.0f, top = 0.0f;
#pragma unroll
        for (int j = 0; j < NE; ++j) {
            float pj = p[j] * inv;
            l_sump[j] += pj;
            ent -= pj * logf(fmaxf(pj, 1e-9f));
            top = fmaxf(top, pj);
        }
        l_ent += ent;
        l_top += top;
#pragma unroll
        for (int j = 0; j < NE; ++j) l_cnt[j] += (am == j) ? 1 : 0;

        if (lane == 0) idx[b] = am;
    }

    if (lane == 0) {
#pragma unroll
        for (int j = 0; j < NE; ++j) if (l_cnt[j]) atomicAdd(&counts[j], l_cnt[j]);
#pragma unroll
        for (int j = 0; j < NE; ++j) atomicAdd(&sump[j], l_sump[j]);
        atomicAdd(zsum, l_z);
        atomicAdd(entsum, l_ent);
        atomicAdd(topsum, l_top);
    }
}

// ---------------- Merge l1 weights: merged = l1_w + tile(l1f_w) ----------------
__global__ __launch_bounds__(256) void merge_kernel(
    const float* __restrict__ l1w, const float* __restrict__ l1b,
    const float* __restrict__ l1fw, const float* __restrict__ l1fb,
    float* __restrict__ mw, float* __restrict__ mb)
{
    const int i = blockIdx.x * 256 + threadIdx.x;
    const int total = NE * NO1 * ND;   // 128*3072
    if (i < total) {
        mw[i] = l1w[i] + l1fw[i % (NO1 * ND)];
    }
    if (i < NE * NO1) {
        mb[i] = l1b[i] + l1fb[i & (NO1 - 1)];
    }
}

// ---------------- Finalize router stats + padded offsets ----------------
__global__ void finalize_kernel(
    const int* __restrict__ counts, const float* __restrict__ sump,
    const float* __restrict__ zsum, const float* __restrict__ entsum,
    const float* __restrict__ topsum, int* __restrict__ offpad,
    float* __restrict__ out)
{
    if (threadIdx.x == 0) {
        int run = 0;
#pragma unroll
        for (int e = 0; e < NE; ++e) {
            offpad[e] = run;
            run += (counts[e] + 31) & ~31;
        }
        offpad[NE] = run;

        float frac[NE], avg[NE];
        float aux = 0.0f;
        const float invB = 1.0f / (float)NB;
#pragma unroll
        for (int e = 0; e < NE; ++e) {
            frac[e] = (float)counts[e] * invB;
            avg[e]  = sump[e] * invB;
            aux += frac[e] * avg[e];
        }
        aux *= (float)NE;
        const float z   = zsum[0] * invB;
        const float ent = entsum[0] * invB;
        const float top = topsum[0] * invB;
        const float rl  = 0.01f * aux + 0.001f * z;

        float* o = out + NB;
        o[0] = rl;
        o[1] = aux;
        o[2] = z;
#pragma unroll
        for (int e = 0; e < NE; ++e) o[3 + e]  = frac[e];
#pragma unroll
        for (int e = 0; e < NE; ++e) o[11 + e] = avg[e];
        o[19] = ent / logf(8.0f);
        o[20] = top;
    }
}

// ---------------- Scatter rows into expert buckets (wave-aggregated atomics) ----------------
__global__ __launch_bounds__(256) void scatter_kernel(
    const int* __restrict__ idx, const int* __restrict__ offpad,
    int* __restrict__ cursors, int* __restrict__ bucket)
{
    const int b = blockIdx.x * 256 + threadIdx.x;
    const int e = idx[b];
    const int lane = threadIdx.x & 63;
    const unsigned long long below = (lane == 63) ? 0xFFFFFFFFFFFFFFFFull >> 1
                                                  : ((1ull << lane) - 1ull);
#pragma unroll
    for (int ee = 0; ee < NE; ++ee) {
        unsigned long long mask = __ballot(e == ee);
        if (e == ee) {
            int leader = __ffsll((unsigned long long)mask) - 1;
            int cnt = __popcll(mask);
            int base = 0;
            if (lane == leader) base = atomicAdd(&cursors[ee], cnt);
            base = __shfl(base, leader);
            int pos = base + __popcll(mask & ((1ull << lane) - 1ull));
            bucket[offpad[ee] + pos] = b;
        }
    }
    (void)below;
}

// ---------------- Main: per 32-row tile, selected-expert l1 GEMV + l2 + l3 ----------------
__global__ __launch_bounds__(256) void moe_main_kernel(
    const float* __restrict__ x, const float* __restrict__ mw,
    const float* __restrict__ mb, const float* __restrict__ l2w,
    const float* __restrict__ l2b, const float* __restrict__ ow,
    const float* __restrict__ ob, const int* __restrict__ bucket,
    const int* __restrict__ offpad, float* __restrict__ out)
{
    __shared__ int   rows_s[32];
    __shared__ int   expert_s;
    __shared__ float part_s[4][32][16];   // per-wave partial l1c
    __shared__ float l1x_s[32][30];
    __shared__ float l1c15_s[32];

    const int t = threadIdx.x;
    const int slot0 = blockIdx.x * 32;
    if (t < 32) rows_s[t] = bucket[slot0 + t];
    if (t == 0) {
        int e = 0;
#pragma unroll
        for (int j = 1; j < NE; ++j) if (slot0 >= offpad[j]) e = j;
        expert_s = e;
    }
    __syncthreads();

    const int e = expert_s;
    const int wave = t >> 6;      // K-quarter
    const int lane = t & 63;
    const int rgrp = lane >> 3;   // 8 row-groups, 4 rows each
    const int s    = lane & 7;    // 8 k-slices (float4 interleave)

    const float* xp[4];
#pragma unroll
    for (int rr = 0; rr < 4; ++rr) {
        int r = rows_s[rgrp * 4 + rr];
        xp[rr] = x + (size_t)(r < 0 ? 0 : r) * ND;
    }
    const float* wb = mw + (size_t)e * NO1 * ND;

    float acc[4][16];
#pragma unroll
    for (int rr = 0; rr < 4; ++rr)
#pragma unroll
        for (int o = 0; o < 16; ++o) acc[rr][o] = 0.0f;

    const int k0 = wave * 768 + s * 4;
    for (int step = 0; step < 24; ++step) {
        const int kb = k0 + step * 32;
        float4 xr[4];
#pragma unroll
        for (int rr = 0; rr < 4; ++rr) xr[rr] = *(const float4*)(xp[rr] + kb);
#pragma unroll
        for (int o = 0; o < 16; ++o) {
            const float4 w = *(const float4*)(wb + o * ND + kb);
#pragma unroll
            for (int rr = 0; rr < 4; ++rr) {
                float a = acc[rr][o];
                a = fmaf(xr[rr].x, w.x, a);
                a = fmaf(xr[rr].y, w.y, a);
                a = fmaf(xr[rr].z, w.z, a);
                a = fmaf(xr[rr].w, w.w, a);
                acc[rr][o] = a;
            }
        }
    }

    // reduce over s (8 k-slices): lanes rgrp*8 + s
#pragma unroll
    for (int rr = 0; rr < 4; ++rr)
#pragma unroll
        for (int o = 0; o < 16; ++o) {
            float a = acc[rr][o];
            a += __shfl_xor(a, 1);
            a += __shfl_xor(a, 2);
            a += __shfl_xor(a, 4);
            acc[rr][o] = a;
        }
    if (s == 0) {
#pragma unroll
        for (int rr = 0; rr < 4; ++rr)
#pragma unroll
            for (int o = 0; o < 16; ++o)
                part_s[wave][rgrp * 4 + rr][o] = acc[rr][o];
    }
    __syncthreads();

    // ---- tail: l1 activation, l2, l3 ----
    const int r = t >> 3;   // row 0..31
    const int q = t & 7;    // 8 threads per row
    const int rowb = rows_s[r];

    if (q < 4) {
#pragma unroll
        for (int oo = 0; oo < 4; ++oo) {
            const int o = q * 4 + oo;
            float v = part_s[0][r][o] + part_s[1][r][o] + part_s[2][r][o]
                    + part_s[3][r][o] + mb[e * NO1 + o];
            if (o < 15) {
                l1x_s[r][o]      = clamp01(v * v * (255.0f / 256.0f));
                l1x_s[r][o + 15] = clamp01(v);
            } else {
                l1c15_s[r] = v;
            }
        }
    }
    __syncthreads();

    float pacc = 0.0f;
    const float* w2 = l2w + (size_t)e * NL3 * NL2D;
#pragma unroll
    for (int oo = 0; oo < 4; ++oo) {
        const int o2 = q + oo * 8;
        float a = l2b[e * NL3 + o2];
        const float* w2r = w2 + o2 * NL2D;
#pragma unroll
        for (int i = 0; i < NL2D; ++i) a = fmaf(l1x_s[r][i], w2r[i], a);
        a = clamp01(a);
        pacc = fmaf(a, ow[e * NL3 + o2], pacc);
    }
    pacc += __shfl_xor(pacc, 1);
    pacc += __shfl_xor(pacc, 2);
    pacc += __shfl_xor(pacc, 4);

    if (q == 0 && rowb >= 0) {
        out[rowb] = pacc + ob[e] + l1c15_s[r];
    }
}

extern "C" void kernel_launch(void* const* d_in, const int* in_sizes, int n_in,
                              void* d_out, int out_size, void* d_ws, size_t ws_size,
                              hipStream_t stream)
{
    const float* x    = (const float*)d_in[0];
    const float* rin  = (const float*)d_in[1];
    const float* rw   = (const float*)d_in[2];
    const float* rb   = (const float*)d_in[3];
    const float* l1w  = (const float*)d_in[4];
    const float* l1b  = (const float*)d_in[5];
    const float* l1fw = (const float*)d_in[6];
    const float* l1fb = (const float*)d_in[7];
    const float* l2w  = (const float*)d_in[8];
    const float* l2b  = (const float*)d_in[9];
    const float* ow   = (const float*)d_in[10];
    const float* ob   = (const float*)d_in[11];
    float* out = (float*)d_out;

    char* ws = (char*)d_ws;
    int*   counts  = (int*)(ws + WS_COUNTS);
    int*   cursors = (int*)(ws + WS_CURSORS);
    float* sump    = (float*)(ws + WS_SUMP);
    float* zsum    = (float*)(ws + WS_ZSUM);
    float* entsum  = (float*)(ws + WS_ENTSUM);
    float* topsum  = (float*)(ws + WS_TOPSUM);
    int*   offpad  = (int*)(ws + WS_OFFPAD);
    int*   idx     = (int*)(ws + WS_IDX);
    int*   bucket  = (int*)(ws + WS_BUCKET);
    float* mb      = (float*)(ws + WS_MB);
    float* mw      = (float*)(ws + WS_MW);

    // zero accumulators/cursors; fill bucket with -1 sentinels
    hipMemsetAsync(ws, 0, 256, stream);
    hipMemsetAsync(ws + WS_BUCKET, 0xFF, (size_t)(NB + 256) * 4, stream);

    router_kernel<<<NB / 64, 256, 0, stream>>>(rin, rw, rb, idx, counts, sump,
                                               zsum, entsum, topsum);
    merge_kernel<<<(NE * NO1 * ND + 255) / 256, 256, 0, stream>>>(l1w, l1b, l1fw, l1fb, mw, mb);
    finalize_kernel<<<1, 64, 0, stream>>>(counts, sump, zsum, entsum, topsum, offpad, out);
    scatter_kernel<<<NB / 256, 256, 0, stream>>>(idx, offpad, cursors, bucket);
    moe_main_kernel<<<(NB + 256) / 32, 256, 0, stream>>>(x, mw, mb, l2w, l2b, ow, ob,
                                                         bucket, offpad, out);
}

// Round 2
// 134.574 us; speedup vs baseline: 2.5051x; 2.5051x over previous
//
#include <hip/hip_runtime.h>

constexpr int NB  = 16384;  // batch
constexpr int ND  = 3072;   // D
constexpr int NR  = 256;    // R
constexpr int NE  = 8;      // experts
constexpr int NO1 = 16;     // L2+1 outputs of l1
constexpr int NL2D = 30;    // 2*L2
constexpr int NL3 = 32;     // L3

// ---- workspace layout (bytes) ----
constexpr size_t WS_COUNTS  = 0;      // int[8] (unused now, kept)
constexpr size_t WS_CURSORS = 32;     // int[8]
constexpr size_t WS_OFFPAD  = 128;    // int[9]
constexpr size_t WS_IDX     = 256;                    // int[NB]
constexpr size_t WS_BUCKET  = WS_IDX + (size_t)NB*4;  // int[NB+256]
constexpr size_t WS_MB      = WS_BUCKET + (size_t)(NB+256)*4; // float[128]
constexpr size_t WS_MW      = WS_MB + 512;            // float[128*3072]
constexpr size_t WS_BLK_CNT  = WS_MW + (size_t)128*3072*4;   // int[256*8]
constexpr size_t WS_BLK_SUMP = WS_BLK_CNT + 8192;            // float[256*8]
constexpr size_t WS_BLK_Z    = WS_BLK_SUMP + 8192;           // float[256]
constexpr size_t WS_BLK_ENT  = WS_BLK_Z + 1024;              // float[256]
constexpr size_t WS_BLK_TOP  = WS_BLK_ENT + 1024;            // float[256]

__device__ __forceinline__ float clamp01(float v) { return fminf(fmaxf(v, 0.0f), 1.0f); }

// ---------------- Router v2: 64 rows/block, 4 threads/row ----------------
__global__ __launch_bounds__(256) void router2_kernel(
    const float* __restrict__ rin, const float* __restrict__ rw,
    const float* __restrict__ rb, int* __restrict__ idx,
    int* __restrict__ blk_cnt, float* __restrict__ blk_sump,
    float* __restrict__ blk_z, float* __restrict__ blk_ent, float* __restrict__ blk_top)
{
    __shared__ float w_s[NE][NR];          // 8 KB
    __shared__ float red_f[4][11];
    __shared__ int   red_c[4][8];

    const int t = threadIdx.x;
    // stage rw (2048 floats = 512 float4)
    {
        const float4* src = (const float4*)rw;
        float4* dst = (float4*)&w_s[0][0];
        dst[t]       = src[t];
        dst[t + 256] = src[t + 256];
    }
    __syncthreads();

    const int q  = t & 3;          // quarter of the row (64 elems each)
    const int rr = t >> 2;         // row within block, 0..63
    const int b  = blockIdx.x * 64 + rr;
    const float* rp = rin + (size_t)b * NR + q * 64;

    float acc[NE];
#pragma unroll
    for (int e = 0; e < NE; ++e) acc[e] = 0.0f;

#pragma unroll
    for (int c = 0; c < 16; ++c) {
        const float4 xv = *(const float4*)(rp + c * 4);
#pragma unroll
        for (int e = 0; e < NE; ++e) {
            const float4 wv = *(const float4*)(&w_s[e][q * 64 + c * 4]);
            acc[e] = fmaf(xv.x, wv.x, acc[e]);
            acc[e] = fmaf(xv.y, wv.y, acc[e]);
            acc[e] = fmaf(xv.z, wv.z, acc[e]);
            acc[e] = fmaf(xv.w, wv.w, acc[e]);
        }
    }
    // butterfly over the 4 q-lanes: all lanes end with the full dot
    float lg[NE];
#pragma unroll
    for (int e = 0; e < NE; ++e) {
        float v = acc[e];
        v += __shfl_xor(v, 1);
        v += __shfl_xor(v, 2);
        lg[e] = v + rb[e];
    }

    // per-row softmax (redundant on 4 lanes; stats masked to q==0)
    float m = lg[0]; int am = 0;
#pragma unroll
    for (int e = 1; e < NE; ++e) { if (lg[e] > m) { m = lg[e]; am = e; } }
    float p[NE]; float ssum = 0.0f;
#pragma unroll
    for (int e = 0; e < NE; ++e) { p[e] = __expf(lg[e] - m); ssum += p[e]; }
    const float inv = 1.0f / ssum;
    const float lse = m + __logf(ssum);

    const bool active = (q == 0);
    float sv[11];
    float ent = 0.0f, top = 0.0f;
#pragma unroll
    for (int e = 0; e < NE; ++e) {
        const float pj = p[e] * inv;
        sv[e] = pj;
        ent -= pj * __logf(fmaxf(pj, 1e-9f));
        top = fmaxf(top, pj);
    }
    sv[8] = lse * lse;
    sv[9] = ent;
    sv[10] = top;
    if (!active) {
#pragma unroll
        for (int i = 0; i < 11; ++i) sv[i] = 0.0f;
    }
    if (active) idx[b] = am;

    // wave reduce (active lanes are multiples of 4 -> offsets 4..32 suffice)
#pragma unroll
    for (int i = 0; i < 11; ++i) {
        float v = sv[i];
        v += __shfl_xor(v, 4);
        v += __shfl_xor(v, 8);
        v += __shfl_xor(v, 16);
        v += __shfl_xor(v, 32);
        sv[i] = v;
    }
    int cnt[NE];
#pragma unroll
    for (int j = 0; j < NE; ++j) {
        unsigned long long mk = __ballot(active && (am == j));
        cnt[j] = __popcll(mk);
    }

    const int wave = t >> 6;
    if ((t & 63) == 0) {
#pragma unroll
        for (int i = 0; i < 11; ++i) red_f[wave][i] = sv[i];
#pragma unroll
        for (int j = 0; j < NE; ++j) red_c[wave][j] = cnt[j];
    }
    __syncthreads();

    const int bid = blockIdx.x;
    if (t < 8) {
        blk_sump[bid * 8 + t] = red_f[0][t] + red_f[1][t] + red_f[2][t] + red_f[3][t];
        blk_cnt [bid * 8 + t] = red_c[0][t] + red_c[1][t] + red_c[2][t] + red_c[3][t];
    } else if (t == 8) {
        blk_z[bid]   = red_f[0][8] + red_f[1][8] + red_f[2][8] + red_f[3][8];
    } else if (t == 9) {
        blk_ent[bid] = red_f[0][9] + red_f[1][9] + red_f[2][9] + red_f[3][9];
    } else if (t == 10) {
        blk_top[bid] = red_f[0][10] + red_f[1][10] + red_f[2][10] + red_f[3][10];
    }
}

// ---------------- Merge l1 weights: merged = l1_w + tile(l1f_w) ----------------
__global__ __launch_bounds__(256) void merge_kernel(
    const float* __restrict__ l1w, const float* __restrict__ l1b,
    const float* __restrict__ l1fw, const float* __restrict__ l1fb,
    float* __restrict__ mw, float* __restrict__ mb)
{
    const int i = blockIdx.x * 256 + threadIdx.x;
    const int total = NE * NO1 * ND;   // 128*3072
    if (i < total) {
        mw[i] = l1w[i] + l1fw[i % (NO1 * ND)];
    }
    if (i < NE * NO1) {
        mb[i] = l1b[i] + l1fb[i & (NO1 - 1)];
    }
}

// ---------------- Finalize v2: reduce 256 per-block partials ----------------
__global__ __launch_bounds__(256) void finalize2_kernel(
    const int* __restrict__ blk_cnt, const float* __restrict__ blk_sump,
    const float* __restrict__ blk_z, const float* __restrict__ blk_ent,
    const float* __restrict__ blk_top, int* __restrict__ offpad,
    float* __restrict__ out)
{
    __shared__ float ps_s[32][8];
    __shared__ int   pc_s[32][8];
    __shared__ float zet_s[3][4];
    __shared__ float tot_f[8];
    __shared__ int   tot_c[8];

    const int t = threadIdx.x;
    {
        const int e = t & 7, g = t >> 3;    // 32 groups of 8 blocks
        float ps = 0.0f; int pc = 0;
#pragma unroll
        for (int k = 0; k < 8; ++k) {
            const int bb = g * 8 + k;
            ps += blk_sump[bb * 8 + e];
            pc += blk_cnt [bb * 8 + e];
        }
        ps_s[g][e] = ps;
        pc_s[g][e] = pc;
    }
    {
        float z = blk_z[t], en = blk_ent[t], tp = blk_top[t];
#pragma unroll
        for (int o = 1; o < 64; o <<= 1) {
            z  += __shfl_xor(z, o);
            en += __shfl_xor(en, o);
            tp += __shfl_xor(tp, o);
        }
        const int wave = t >> 6;
        if ((t & 63) == 0) { zet_s[0][wave] = z; zet_s[1][wave] = en; zet_s[2][wave] = tp; }
    }
    __syncthreads();

    if (t < 8) {
        float s = 0.0f; int c = 0;
        for (int g = 0; g < 32; ++g) { s += ps_s[g][t]; c += pc_s[g][t]; }
        tot_f[t] = s; tot_c[t] = c;
    }
    __syncthreads();

    if (t == 0) {
        int run = 0;
#pragma unroll
        for (int e = 0; e < NE; ++e) {
            offpad[e] = run;
            run += (tot_c[e] + 31) & ~31;
        }
        offpad[NE] = run;

        const float invB = 1.0f / (float)NB;
        float aux = 0.0f;
        float frac[NE], avg[NE];
#pragma unroll
        for (int e = 0; e < NE; ++e) {
            frac[e] = (float)tot_c[e] * invB;
            avg[e]  = tot_f[e] * invB;
            aux += frac[e] * avg[e];
        }
        aux *= (float)NE;
        const float z   = (zet_s[0][0] + zet_s[0][1] + zet_s[0][2] + zet_s[0][3]) * invB;
        const float ent = (zet_s[1][0] + zet_s[1][1] + zet_s[1][2] + zet_s[1][3]) * invB;
        const float top = (zet_s[2][0] + zet_s[2][1] + zet_s[2][2] + zet_s[2][3]) * invB;
        const float rl  = 0.01f * aux + 0.001f * z;

        float* o = out + NB;
        o[0] = rl;
        o[1] = aux;
        o[2] = z;
#pragma unroll
        for (int e = 0; e < NE; ++e) o[3 + e]  = frac[e];
#pragma unroll
        for (int e = 0; e < NE; ++e) o[11 + e] = avg[e];
        o[19] = ent / __logf(8.0f);
        o[20] = top;
    }
}

// ---------------- Scatter rows into expert buckets (wave-aggregated atomics) ----------------
__global__ __launch_bounds__(256) void scatter_kernel(
    const int* __restrict__ idx, const int* __restrict__ offpad,
    int* __restrict__ cursors, int* __restrict__ bucket)
{
    const int b = blockIdx.x * 256 + threadIdx.x;
    const int e = idx[b];
    const int lane = threadIdx.x & 63;
#pragma unroll
    for (int ee = 0; ee < NE; ++ee) {
        unsigned long long mask = __ballot(e == ee);
        if (e == ee) {
            int leader = __ffsll((unsigned long long)mask) - 1;
            int cnt = __popcll(mask);
            int base = 0;
            if (lane == leader) base = atomicAdd(&cursors[ee], cnt);
            base = __shfl(base, leader);
            int pos = base + __popcll(mask & ((1ull << lane) - 1ull));
            bucket[offpad[ee] + pos] = b;
        }
    }
}

// ---------------- Main: per 32-row tile, selected-expert l1 GEMV + l2 + l3 ----------------
__global__ __launch_bounds__(256) void moe_main_kernel(
    const float* __restrict__ x, const float* __restrict__ mw,
    const float* __restrict__ mb, const float* __restrict__ l2w,
    const float* __restrict__ l2b, const float* __restrict__ ow,
    const float* __restrict__ ob, const int* __restrict__ bucket,
    const int* __restrict__ offpad, float* __restrict__ out)
{
    __shared__ int   rows_s[32];
    __shared__ int   expert_s;
    __shared__ float part_s[4][32][16];   // per-wave partial l1c
    __shared__ float l1x_s[32][30];
    __shared__ float l1c15_s[32];

    const int t = threadIdx.x;
    const int slot0 = blockIdx.x * 32;
    if (t < 32) rows_s[t] = bucket[slot0 + t];
    if (t == 0) {
        int e = 0;
#pragma unroll
        for (int j = 1; j < NE; ++j) if (slot0 >= offpad[j]) e = j;
        expert_s = e;
    }
    __syncthreads();

    const int e = expert_s;
    const int wave = t >> 6;      // K-quarter
    const int lane = t & 63;
    const int rgrp = lane >> 3;   // 8 row-groups, 4 rows each
    const int s    = lane & 7;    // 8 k-slices (float4 interleave)

    const float* xp[4];
#pragma unroll
    for (int rr = 0; rr < 4; ++rr) {
        int r = rows_s[rgrp * 4 + rr];
        xp[rr] = x + (size_t)(r < 0 ? 0 : r) * ND;
    }
    const float* wb = mw + (size_t)e * NO1 * ND;

    float acc[4][16];
#pragma unroll
    for (int rr = 0; rr < 4; ++rr)
#pragma unroll
        for (int o = 0; o < 16; ++o) acc[rr][o] = 0.0f;

    const int k0 = wave * 768 + s * 4;
    for (int step = 0; step < 24; ++step) {
        const int kb = k0 + step * 32;
        float4 xr[4];
#pragma unroll
        for (int rr = 0; rr < 4; ++rr) xr[rr] = *(const float4*)(xp[rr] + kb);
#pragma unroll
        for (int o = 0; o < 16; ++o) {
            const float4 w = *(const float4*)(wb + o * ND + kb);
#pragma unroll
            for (int rr = 0; rr < 4; ++rr) {
                float a = acc[rr][o];
                a = fmaf(xr[rr].x, w.x, a);
                a = fmaf(xr[rr].y, w.y, a);
                a = fmaf(xr[rr].z, w.z, a);
                a = fmaf(xr[rr].w, w.w, a);
                acc[rr][o] = a;
            }
        }
    }

    // reduce over s (8 k-slices)
#pragma unroll
    for (int rr = 0; rr < 4; ++rr)
#pragma unroll
        for (int o = 0; o < 16; ++o) {
            float a = acc[rr][o];
            a += __shfl_xor(a, 1);
            a += __shfl_xor(a, 2);
            a += __shfl_xor(a, 4);
            acc[rr][o] = a;
        }
    if (s == 0) {
#pragma unroll
        for (int rr = 0; rr < 4; ++rr)
#pragma unroll
            for (int o = 0; o < 16; ++o)
                part_s[wave][rgrp * 4 + rr][o] = acc[rr][o];
    }
    __syncthreads();

    // ---- tail: l1 activation, l2, l3 ----
    const int r = t >> 3;   // row 0..31
    const int q = t & 7;    // 8 threads per row
    const int rowb = rows_s[r];

    if (q < 4) {
#pragma unroll
        for (int oo = 0; oo < 4; ++oo) {
            const int o = q * 4 + oo;
            float v = part_s[0][r][o] + part_s[1][r][o] + part_s[2][r][o]
                    + part_s[3][r][o] + mb[e * NO1 + o];
            if (o < 15) {
                l1x_s[r][o]      = clamp01(v * v * (255.0f / 256.0f));
                l1x_s[r][o + 15] = clamp01(v);
            } else {
                l1c15_s[r] = v;
            }
        }
    }
    __syncthreads();

    float pacc = 0.0f;
    const float* w2 = l2w + (size_t)e * NL3 * NL2D;
#pragma unroll
    for (int oo = 0; oo < 4; ++oo) {
        const int o2 = q + oo * 8;
        float a = l2b[e * NL3 + o2];
        const float* w2r = w2 + o2 * NL2D;
#pragma unroll
        for (int i = 0; i < NL2D; ++i) a = fmaf(l1x_s[r][i], w2r[i], a);
        a = clamp01(a);
        pacc = fmaf(a, ow[e * NL3 + o2], pacc);
    }
    pacc += __shfl_xor(pacc, 1);
    pacc += __shfl_xor(pacc, 2);
    pacc += __shfl_xor(pacc, 4);

    if (q == 0 && rowb >= 0) {
        out[rowb] = pacc + ob[e] + l1c15_s[r];
    }
}

extern "C" void kernel_launch(void* const* d_in, const int* in_sizes, int n_in,
                              void* d_out, int out_size, void* d_ws, size_t ws_size,
                              hipStream_t stream)
{
    const float* x    = (const float*)d_in[0];
    const float* rin  = (const float*)d_in[1];
    const float* rw   = (const float*)d_in[2];
    const float* rb   = (const float*)d_in[3];
    const float* l1w  = (const float*)d_in[4];
    const float* l1b  = (const float*)d_in[5];
    const float* l1fw = (const float*)d_in[6];
    const float* l1fb = (const float*)d_in[7];
    const float* l2w  = (const float*)d_in[8];
    const float* l2b  = (const float*)d_in[9];
    const float* ow   = (const float*)d_in[10];
    const float* ob   = (const float*)d_in[11];
    float* out = (float*)d_out;

    char* ws = (char*)d_ws;
    int*   cursors = (int*)(ws + WS_CURSORS);
    int*   offpad  = (int*)(ws + WS_OFFPAD);
    int*   idx     = (int*)(ws + WS_IDX);
    int*   bucket  = (int*)(ws + WS_BUCKET);
    float* mb      = (float*)(ws + WS_MB);
    float* mw      = (float*)(ws + WS_MW);
    int*   blk_cnt  = (int*)(ws + WS_BLK_CNT);
    float* blk_sump = (float*)(ws + WS_BLK_SUMP);
    float* blk_z    = (float*)(ws + WS_BLK_Z);
    float* blk_ent  = (float*)(ws + WS_BLK_ENT);
    float* blk_top  = (float*)(ws + WS_BLK_TOP);

    // zero cursors; fill bucket with -1 sentinels
    hipMemsetAsync(ws, 0, 256, stream);
    hipMemsetAsync(ws + WS_BUCKET, 0xFF, (size_t)(NB + 256) * 4, stream);

    router2_kernel<<<NB / 64, 256, 0, stream>>>(rin, rw, rb, idx, blk_cnt, blk_sump,
                                                blk_z, blk_ent, blk_top);
    merge_kernel<<<(NE * NO1 * ND + 255) / 256, 256, 0, stream>>>(l1w, l1b, l1fw, l1fb, mw, mb);
    finalize2_kernel<<<1, 256, 0, stream>>>(blk_cnt, blk_sump, blk_z, blk_ent, blk_top,
                                            offpad, out);
    scatter_kernel<<<NB / 256, 256, 0, stream>>>(idx, offpad, cursors, bucket);
    moe_main_kernel<<<(NB + 256) / 32, 256, 0, stream>>>(x, mw, mb, l2w, l2b, ow, ob,
                                                         bucket, offpad, out);
}